// Round 1
// baseline (179.556 us; speedup 1.0000x reference)
//
#include <hip/hip_runtime.h>

#define NVAR   576
#define NROW   144
#define DEG    15
#define NEDGE  (NROW * DEG)   // 2160
#define NBATCH 256
#define NITER  3

// Kernel 1: extract sparse structure of H (15 column indices per row).
__global__ void build_cols_kernel(const float* __restrict__ H,
                                  short* __restrict__ cols) {
    int m = blockIdx.x * blockDim.x + threadIdx.x;
    if (m >= NROW) return;
    const float* Hr = H + m * NVAR;
    int k = 0;
    for (int n = 0; n < NVAR; ++n) {
        if (Hr[n] != 0.0f) {
            cols[m * DEG + k] = (short)n;
            if (++k == DEG) break;
        }
    }
}

// Kernel 2: one block per batch element; whole decode in LDS.
__launch_bounds__(256, 1)
__global__ void ldpc_minsum_kernel(const float* __restrict__ r,
                                   const short* __restrict__ cols_g,
                                   const float* __restrict__ alpha,
                                   const float* __restrict__ beta,
                                   float* __restrict__ out) {
    __shared__ float rs[NVAR];
    __shared__ float sumE[NVAR];
    __shared__ short cols[NEDGE];
    __shared__ float Msh[NEDGE];
    __shared__ float Esh[NEDGE];
    __shared__ float rmin1[NROW];
    __shared__ float rmin2[NROW];
    __shared__ float rsign[NROW];
    __shared__ short rj1[NROW];

    const int b = blockIdx.x;
    const int t = threadIdx.x;
    const int NT = 256;

    // Stage r row + edge structure into LDS (coalesced global reads).
    for (int n = t; n < NVAR; n += NT) rs[n] = r[b * NVAR + n];
    for (int e = t; e < NEDGE; e += NT) cols[e] = cols_g[e];
    __syncthreads();

    // M0 = H * r  (edge-compressed)
    for (int e = t; e < NEDGE; e += NT) Msh[e] = rs[cols[e]];
    __syncthreads();

    for (int it = 0; it < NITER; ++it) {
        const float al = alpha[it];
        const float be = beta[it];

        // Per-row reduction: min1, min2, argmin position, sign parity.
        if (t < NROW) {
            float m1 = INFINITY, m2 = INFINITY, sg = 1.0f;
            int j1 = 0;
            const float* Mr = &Msh[t * DEG];
            #pragma unroll
            for (int j = 0; j < DEG; ++j) {
                float v = Mr[j];
                float a = fabsf(v);
                float s = (v > 0.0f) ? 1.0f : ((v < 0.0f) ? -1.0f : 0.0f);
                sg *= s;
                if (a < m1) { m2 = m1; m1 = a; j1 = j; }
                else if (a < m2) { m2 = a; }
            }
            rmin1[t] = m1;
            rmin2[t] = m2;
            rsign[t] = sg;
            rj1[t]  = (short)j1;
        }
        // Concurrently zero the column accumulator (disjoint arrays).
        for (int n = t; n < NVAR; n += NT) sumE[n] = 0.0f;
        __syncthreads();

        // Per-edge E value + column scatter-sum.
        for (int e = t; e < NEDGE; e += NT) {
            int m = e / DEG;
            int j = e - m * DEG;
            float v = Msh[e];
            float s = (v > 0.0f) ? 1.0f : ((v < 0.0f) ? -1.0f : 0.0f);
            float eabs = (j == (int)rj1[m]) ? rmin2[m] : rmin1[m];
            float ev = al * rsign[m] * s * fmaxf(0.0f, eabs - be);
            Esh[e] = ev;
            atomicAdd(&sumE[cols[e]], ev);
        }
        __syncthreads();

        if (it == NITER - 1) {
            // Output: r + column-sum of final E.
            for (int n = t; n < NVAR; n += NT)
                out[b * NVAR + n] = rs[n] + sumE[n];
        } else {
            // Variable-to-check update: M = r + sumE - E (at edges).
            for (int e = t; e < NEDGE; e += NT)
                Msh[e] = rs[cols[e]] + sumE[cols[e]] - Esh[e];
            __syncthreads();
        }
    }
}

extern "C" void kernel_launch(void* const* d_in, const int* in_sizes, int n_in,
                              void* d_out, int out_size, void* d_ws, size_t ws_size,
                              hipStream_t stream) {
    const float* r     = (const float*)d_in[0];
    const float* H     = (const float*)d_in[1];
    const float* alpha = (const float*)d_in[2];
    const float* beta  = (const float*)d_in[3];
    float* out  = (float*)d_out;
    short* cols = (short*)d_ws;   // 2160 * 2 B = 4320 B of scratch

    build_cols_kernel<<<(NROW + 63) / 64, 64, 0, stream>>>(H, cols);
    ldpc_minsum_kernel<<<NBATCH, 256, 0, stream>>>(r, cols, alpha, beta, out);
}

// Round 2
// 77.928 us; speedup vs baseline: 2.3041x; 2.3041x over previous
//
#include <hip/hip_runtime.h>

#define NVAR   576
#define NROW   144
#define DEG    15
#define NEDGE  (NROW * DEG)   // 2160
#define NBATCH 256
#define NITER  3
#define NT     576            // decode block size: one thread per variable node
#define EPT    4              // max edges per thread: ceil(2160/576)

// Kernel 1: extract sparse structure of H. One wave per row; ballot-compaction
// preserves ascending column order (matches top_k lowest-index tie-breaking).
__global__ void build_cols_kernel(const float* __restrict__ H,
                                  short* __restrict__ cols) {
    int gid  = blockIdx.x * blockDim.x + threadIdx.x;
    int wid  = gid >> 6;          // wave id == row id
    int lane = gid & 63;
    if (wid >= NROW) return;
    const float* Hr = H + wid * NVAR;
    int base = 0;
    #pragma unroll
    for (int c = 0; c < NVAR / 64; ++c) {
        float h = Hr[c * 64 + lane];
        unsigned long long m = __ballot(h != 0.0f);
        int rank = __popcll(m & ((1ull << lane) - 1ull));
        if (h != 0.0f) cols[wid * DEG + base + rank] = (short)(c * 64 + lane);
        base += __popcll(m);      // wave-uniform
    }
}

// Kernel 2: one block (576 threads, 9 waves) per batch element.
// Per-edge state lives in registers; LDS holds only what crosses threads.
__launch_bounds__(NT, 1)
__global__ void ldpc_minsum_kernel(const float* __restrict__ r,
                                   const short* __restrict__ cols_g,
                                   const float* __restrict__ alpha,
                                   const float* __restrict__ beta,
                                   float* __restrict__ out) {
    __shared__ float  rs[NVAR];
    __shared__ float  sumE[NVAR];
    __shared__ float  rnew[NVAR];
    __shared__ short  cols[NEDGE];
    __shared__ float  Msh[NEDGE];          // read by row-reduce threads
    __shared__ float4 rowdat[NROW];        // {min1, min2, sign, argmin-bits}

    const int b = blockIdx.x;
    const int t = threadIdx.x;

    // Hoist alpha/beta into registers (unrolled -> no global loads in loop).
    float alr[NITER], ber[NITER];
    #pragma unroll
    for (int i = 0; i < NITER; ++i) { alr[i] = alpha[i]; ber[i] = beta[i]; }

    // Stage r row + edge structure.
    rs[t] = r[b * NVAR + t];
    #pragma unroll
    for (int k = 0; k < EPT; ++k) {
        int e = t + k * NT;
        if (e < NEDGE) cols[e] = cols_g[e];
    }
    __syncthreads();

    // Per-thread edge metadata in registers.
    int ec[EPT], em[EPT], ej[EPT];
    float mv[EPT], ev[EPT];
    #pragma unroll
    for (int k = 0; k < EPT; ++k) {
        int e = t + k * NT;
        if (e < NEDGE) {
            int c = cols[e];
            int m = e / DEG;
            ec[k] = c; em[k] = m; ej[k] = e - m * DEG;
            float v = rs[c];           // M0 = H*r at edges
            mv[k] = v;
            Msh[e] = v;
        }
    }
    __syncthreads();

    #pragma unroll
    for (int it = 0; it < NITER; ++it) {
        // Per-row reduction: min1, min2, argmin, sign parity (144 threads).
        if (t < NROW) {
            float m1 = INFINITY, m2 = INFINITY, sg = 1.0f;
            int j1 = 0;
            const float* Mr = &Msh[t * DEG];
            #pragma unroll
            for (int j = 0; j < DEG; ++j) {
                float v = Mr[j];
                float a = fabsf(v);
                float s = (v > 0.0f) ? 1.0f : ((v < 0.0f) ? -1.0f : 0.0f);
                sg *= s;
                if (a < m1) { m2 = m1; m1 = a; j1 = j; }
                else if (a < m2) { m2 = a; }
            }
            rowdat[t] = make_float4(m1, m2, sg, __int_as_float(j1));
        }
        sumE[t] = 0.0f;   // disjoint from row-reduce; same region
        __syncthreads();

        // Per-edge E + column scatter-sum (E stays in registers).
        #pragma unroll
        for (int k = 0; k < EPT; ++k) {
            int e = t + k * NT;
            if (e < NEDGE) {
                float v = mv[k];
                float4 rd = rowdat[em[k]];
                float s = (v > 0.0f) ? 1.0f : ((v < 0.0f) ? -1.0f : 0.0f);
                float eabs = (ej[k] == __float_as_int(rd.w)) ? rd.y : rd.x;
                float e_ = alr[it] * rd.z * s * fmaxf(0.0f, eabs - ber[it]);
                ev[k] = e_;
                atomicAdd(&sumE[ec[k]], e_);
            }
        }
        __syncthreads();

        float v = rs[t] + sumE[t];
        if (it == NITER - 1) {
            out[b * NVAR + t] = v;      // final posterior
        } else {
            rnew[t] = v;
            __syncthreads();
            // Variable-to-check update: M = (r + sumE) - E at edges.
            #pragma unroll
            for (int k = 0; k < EPT; ++k) {
                int e = t + k * NT;
                if (e < NEDGE) {
                    float nv = rnew[ec[k]] - ev[k];
                    mv[k] = nv;
                    Msh[e] = nv;
                }
            }
            __syncthreads();
        }
    }
}

extern "C" void kernel_launch(void* const* d_in, const int* in_sizes, int n_in,
                              void* d_out, int out_size, void* d_ws, size_t ws_size,
                              hipStream_t stream) {
    const float* r     = (const float*)d_in[0];
    const float* H     = (const float*)d_in[1];
    const float* alpha = (const float*)d_in[2];
    const float* beta  = (const float*)d_in[3];
    float* out  = (float*)d_out;
    short* cols = (short*)d_ws;   // 2160 * 2 B scratch

    // 144 waves total: 36 blocks x 256 threads, one wave per row.
    build_cols_kernel<<<36, 256, 0, stream>>>(H, cols);
    ldpc_minsum_kernel<<<NBATCH, NT, 0, stream>>>(r, cols, alpha, beta, out);
}

// Round 3
// 75.133 us; speedup vs baseline: 2.3898x; 1.0372x over previous
//
#include <hip/hip_runtime.h>

#define NVAR   576
#define NROW   144
#define DEG    15
#define NEDGE  (NROW * DEG)   // 2160
#define NBATCH 256
#define NITER  3
#define NT     192            // decode block: 3 waves; t<144 owns a row

// Kernel 1: extract sparse structure of H. One wave per row; ballot-compaction
// preserves ascending column order (matches top_k lowest-index tie-breaking).
__global__ void build_cols_kernel(const float* __restrict__ H,
                                  short* __restrict__ cols) {
    int gid  = blockIdx.x * blockDim.x + threadIdx.x;
    int wid  = gid >> 6;          // wave id == row id
    int lane = gid & 63;
    if (wid >= NROW) return;
    const float* Hr = H + wid * NVAR;
    int base = 0;
    #pragma unroll
    for (int c = 0; c < NVAR / 64; ++c) {
        float h = Hr[c * 64 + lane];
        unsigned long long m = __ballot(h != 0.0f);
        int rank = __popcll(m & ((1ull << lane) - 1ull));
        if (h != 0.0f) cols[wid * DEG + base + rank] = (short)(c * 64 + lane);
        base += __popcll(m);      // wave-uniform
    }
}

// Kernel 2: one block per batch element. Row-centric: thread t<144 owns row t
// entirely in registers (cols, M, E, r-at-cols). LDS holds only rs + two
// ping-pong column accumulators. Two 3-wave barriers per iteration.
__launch_bounds__(NT, 1)
__global__ void ldpc_minsum_kernel(const float* __restrict__ r,
                                   const short* __restrict__ cols_g,
                                   const float* __restrict__ alpha,
                                   const float* __restrict__ beta,
                                   float* __restrict__ out) {
    __shared__ float rs[NVAR];
    __shared__ float sA[NVAR];    // ping-pong column accumulators
    __shared__ float sB[NVAR];

    const int b = blockIdx.x;
    const int t = threadIdx.x;

    float alr[NITER], ber[NITER];
    #pragma unroll
    for (int i = 0; i < NITER; ++i) { alr[i] = alpha[i]; ber[i] = beta[i]; }

    // Stage r (coalesced) and zero the first accumulator.
    #pragma unroll
    for (int k = 0; k < 3; ++k) {
        int n = t + k * NT;
        rs[n] = r[b * NVAR + n];
        sA[n] = 0.0f;
    }
    __syncthreads();

    // Row-owned register state.
    int   ci[DEG];
    float Mv[DEG], Ev[DEG], rc[DEG];
    if (t < NROW) {
        #pragma unroll
        for (int j = 0; j < DEG; ++j) ci[j] = (int)cols_g[t * DEG + j];
        #pragma unroll
        for (int j = 0; j < DEG; ++j) { rc[j] = rs[ci[j]]; Mv[j] = rc[j]; }
    }

    #pragma unroll
    for (int it = 0; it < NITER; ++it) {
        float* sum = (it & 1) ? sB : sA;   // scatter target (pre-zeroed)
        float* nxt = (it & 1) ? sA : sB;   // zeroed this iter for next scatter

        if (t < NROW) {
            // In-register min1/min2/argmin/sign-parity reduce over 15 edges.
            float m1 = INFINITY, m2 = INFINITY, sg = 1.0f;
            int j1 = 0;
            #pragma unroll
            for (int j = 0; j < DEG; ++j) {
                float v = Mv[j];
                float a = fabsf(v);
                float s = (v > 0.0f) ? 1.0f : ((v < 0.0f) ? -1.0f : 0.0f);
                sg *= s;
                if (a < m1) { m2 = m1; m1 = a; j1 = j; }
                else if (a < m2) { m2 = a; }
            }
            // E values + column scatter (E stays in registers).
            #pragma unroll
            for (int j = 0; j < DEG; ++j) {
                float v = Mv[j];
                float s = (v > 0.0f) ? 1.0f : ((v < 0.0f) ? -1.0f : 0.0f);
                float eabs = (j == j1) ? m2 : m1;
                float e = alr[it] * sg * s * fmaxf(0.0f, eabs - ber[it]);
                Ev[j] = e;
                atomicAdd(&sum[ci[j]], e);
            }
        }
        __syncthreads();   // drain scatter

        if (it == NITER - 1) {
            #pragma unroll
            for (int k = 0; k < 3; ++k) {
                int n = t + k * NT;
                out[b * NVAR + n] = rs[n] + sum[n];
            }
        } else {
            // Zero the other buffer for the next iteration (disjoint from sum).
            #pragma unroll
            for (int k = 0; k < 3; ++k) nxt[t + k * NT] = 0.0f;
            // In-register M update: M = r + sumE - E at this row's columns.
            if (t < NROW) {
                #pragma unroll
                for (int j = 0; j < DEG; ++j)
                    Mv[j] = rc[j] + sum[ci[j]] - Ev[j];
            }
            __syncthreads();
        }
    }
}

extern "C" void kernel_launch(void* const* d_in, const int* in_sizes, int n_in,
                              void* d_out, int out_size, void* d_ws, size_t ws_size,
                              hipStream_t stream) {
    const float* r     = (const float*)d_in[0];
    const float* H     = (const float*)d_in[1];
    const float* alpha = (const float*)d_in[2];
    const float* beta  = (const float*)d_in[3];
    float* out  = (float*)d_out;
    short* cols = (short*)d_ws;   // 2160 * 2 B scratch

    build_cols_kernel<<<36, 256, 0, stream>>>(H, cols);
    ldpc_minsum_kernel<<<NBATCH, NT, 0, stream>>>(r, cols, alpha, beta, out);
}